// Round 4
// baseline (328.390 us; speedup 1.0000x reference)
//
#include <hip/hip_runtime.h>

// SSIM3D, (4,1,128,128,128) fp32, separable 11-tap Gaussian, scalar mean out.
//
//  A: x-conv + y-conv fused (sliding-window accs over y), 5 fields -> ws
//     staging via global_load_lds DMA (no predication, no VGPR round-trip)
//  B: z-conv + SSIM map + block reduction (sliding-window accs over z),
//     batches in reverse order so A's freshest output is L3-resident
//  C: final reduce
//
// R3 lesson: predicated scalar staging + xh split = latency-bound (3.1 TB/s,
// 22% VALU) + 2.2x write amplification (spills). This round: DMA staging,
// full-x rows, even-aligned float2 LDS reads via shifted 12-tap weights.

#define SLICE (128*128)        // 16384
#define S  (128*SLICE)         // 2097152 per field per batch
#define C1_ 0.0001f
#define C2_ 0.0009f

typedef unsigned int u32;

__device__ __forceinline__ void gload_lds(const float* g, float* l) {
    __builtin_amdgcn_global_load_lds(
        (const __attribute__((address_space(1))) u32*)g,
        (__attribute__((address_space(3))) u32*)l, 4, 0, 0);
}

__device__ __forceinline__ void make_g(float* g) {
    float s = 0.f;
#pragma unroll
    for (int i = 0; i < 11; ++i) {
        float d = (float)(i - 5);
        g[i] = __expf(-d * d / 4.5f);
        s += g[i];
    }
    float inv = 1.f / s;
#pragma unroll
    for (int i = 0; i < 11; ++i) g[i] *= inv;
}

// ---------------- Kernel A: x-conv + y-conv, walk y ----------------
// grid: 4n * 128z * 4yc = 2048 blocks of 128 threads (2 waves).
// Thread owns x = tid, walks 32 y outputs (42 steps in 4 phases of 11).
// LDS rows[t][img][140]: s = 5 + x; pads s<5 and s>132 are zeros (x halo).
__global__ __launch_bounds__(128, 4)
void ssimA(const float* __restrict__ img1, const float* __restrict__ img2,
           float* __restrict__ fields) {
    __shared__ float rows[11][2][140];
    float g[11]; make_g(g);
    const int tid = threadIdx.x;
    const int w = tid >> 6, ln = tid & 63;
    const int x = tid;                       // 0..127
    const int b = blockIdx.x;
    const int yc = b & 3, z = (b >> 2) & 127, n = b >> 9;
    const int y0 = yc * 32;
    const float* p1 = img1 + (size_t)n * S + (size_t)z * SLICE;
    const float* p2 = img2 + (size_t)n * S + (size_t)z * SLICE;
    float* fb = fields + (size_t)n * 5 * S + (size_t)z * SLICE + x;

    // 12-tap shifted weights over the even-aligned window [x&~1, x&~1+11]
    // (value for s = x + j has tap weight g[j]; even base shifts odd x by 1;
    //  x-boundary taps read zero pads so no extra masking needed)
    float w12[12];
    {
        const int odd = x & 1;
#pragma unroll
        for (int j = 0; j < 12; ++j) {
            float v = 0.f;
            if (odd) { if (j >= 1) v = g[j - 1]; }
            else     { if (j < 11) v = g[j]; }
            w12[j] = v;
        }
    }
    const int s0 = x & ~1;

    // zero the pads once: per (t,i), s in {0..4} U {133..139}
    for (int idx = tid; idx < 11 * 2 * 12; idx += 128) {
        int t = idx / 24, rem = idx % 24, i = rem / 12, p = rem % 12;
        int s = (p < 5) ? p : (128 + p);
        rows[t][i][s] = 0.f;
    }

    float acc[5][11];
#pragma unroll
    for (int f = 0; f < 5; ++f)
#pragma unroll
        for (int s2 = 0; s2 < 11; ++s2) acc[f][s2] = 0.f;

#pragma unroll 1
    for (int blk = 0; blk < 4; ++blk) {
        __syncthreads();   // rows reuse (and pad init on first iter)
        // ---- stage 11 rows x 2 imgs via DMA: wave w covers x in [64w,64w+64)
#pragma unroll
        for (int t = 0; t < 11; ++t) {
            int y_in = y0 + blk * 11 + t - 5;
            int ycl = min(max(y_in, 0), 127);
            const float* r1 = p1 + (size_t)ycl * 128 + (w * 64 + ln);
            const float* r2 = p2 + (size_t)ycl * 128 + (w * 64 + ln);
            gload_lds(r1, &rows[t][0][5 + w * 64]);
            gload_lds(r2, &rows[t][1][5 + w * 64]);
        }
        __syncthreads();   // drains DMA (compiler emits vmcnt(0) before barrier)
        // ---- compute 11 steps
#pragma unroll
        for (int t = 0; t < 11; ++t) {
            int step = blk * 11 + t;
            if (step >= 42) continue;            // wave-uniform (last phase)
            int y_in = y0 + step - 5;
            bool row_ok = (y_in >= 0) && (y_in < 128);

            float2 va[6], vb[6];
#pragma unroll
            for (int m = 0; m < 6; ++m) {
                va[m] = *(const float2*)&rows[t][0][s0 + 2 * m];
                vb[m] = *(const float2*)&rows[t][1][s0 + 2 * m];
            }
            const float* fa = (const float*)va;
            const float* fc = (const float*)vb;
            float u1 = 0, u2 = 0, a11 = 0, a22 = 0, a12 = 0;
#pragma unroll
            for (int j = 0; j < 12; ++j) {
                float wj = w12[j];
                float a_ = fa[j], b_ = fc[j];
                float ta = wj * a_, tb = wj * b_;
                u1 += ta; u2 += tb;
                a11 = fmaf(ta, a_, a11);
                a12 = fmaf(ta, b_, a12);
                a22 = fmaf(tb, b_, a22);
            }
            // y-accumulate: slot (t+j+1)%11 static under the unroll
#pragma unroll
            for (int j = 0; j < 11; ++j) {
                int oo = step - 10 + j;
                float wy = (row_ok && oo >= 0 && oo < 32) ? g[10 - j] : 0.f;
                const int sl = (t + j + 1) % 11;
                acc[0][sl] = fmaf(wy, u1,  acc[0][sl]);
                acc[1][sl] = fmaf(wy, u2,  acc[1][sl]);
                acc[2][sl] = fmaf(wy, a11, acc[2][sl]);
                acc[3][sl] = fmaf(wy, a22, acc[3][sl]);
                acc[4][sl] = fmaf(wy, a12, acc[4][sl]);
            }
            if (step >= 10) {
                const int es = (t + 1) % 11;     // static
                size_t ro = (size_t)(y0 + step - 10) * 128;
#pragma unroll
                for (int f = 0; f < 5; ++f) {
                    fb[(size_t)f * S + ro] = acc[f][es];
                    acc[f][es] = 0.f;
                }
            }
        }
    }
}

// ---------------- Kernel B: z-conv + map + reduce, walk z ----------------
// grid: 4n * 128y * 4zc = 2048 blocks of 128 threads; thread owns x = tid.
// Batches in REVERSE (freshest A output first -> L3 hits).
__global__ __launch_bounds__(128, 4)
void ssimB(const float* __restrict__ fields, float* __restrict__ partials) {
    float g[11]; make_g(g);
    const int tid = threadIdx.x;
    const int b = blockIdx.x;
    const int zc = b & 3, y = (b >> 2) & 127;
    const int n = 3 - (b >> 9);
    const int z0 = zc * 32;
    const float* base = fields + (size_t)n * 5 * S + (size_t)y * 128 + tid;

    float acc[5][11];
#pragma unroll
    for (int f = 0; f < 5; ++f)
#pragma unroll
        for (int s2 = 0; s2 < 11; ++s2) acc[f][s2] = 0.f;

    float sum = 0.f;

#pragma unroll 1
    for (int blk = 0; blk < 4; ++blk) {
#pragma unroll
        for (int t = 0; t < 11; ++t) {
            int step = blk * 11 + t;
            int z_in = z0 + step - 5;
            int zcl = min(max(z_in, 0), 127);
            bool row_ok = (z_in >= 0) && (z_in < 128);
            size_t off = (size_t)zcl * SLICE;
            float f0 = base[0 * (size_t)S + off];
            float f1 = base[1 * (size_t)S + off];
            float f2 = base[2 * (size_t)S + off];
            float f3 = base[3 * (size_t)S + off];
            float f4 = base[4 * (size_t)S + off];
            if (step >= 42) continue;            // wave-uniform
#pragma unroll
            for (int j = 0; j < 11; ++j) {
                int oo = step - 10 + j;
                float wz = (row_ok && oo >= 0 && oo < 32) ? g[10 - j] : 0.f;
                const int sl = (t + j + 1) % 11;
                acc[0][sl] = fmaf(wz, f0, acc[0][sl]);
                acc[1][sl] = fmaf(wz, f1, acc[1][sl]);
                acc[2][sl] = fmaf(wz, f2, acc[2][sl]);
                acc[3][sl] = fmaf(wz, f3, acc[3][sl]);
                acc[4][sl] = fmaf(wz, f4, acc[4][sl]);
            }
            if (step >= 10) {
                const int es = (t + 1) % 11;     // static
                float m1 = acc[0][es], m2 = acc[1][es];
                float p11 = acc[2][es], p22 = acc[3][es];
                float p12 = acc[4][es];
                float m1s = m1 * m1, m2s = m2 * m2, m12 = m1 * m2;
                float v1 = p11 - m1s, v2 = p22 - m2s, cv = p12 - m12;
                float num = (2.f * m12 + C1_) * (2.f * cv + C2_);
                float den = (m1s + m2s + C1_) * (v1 + v2 + C2_);
                sum += num / den;
#pragma unroll
                for (int f = 0; f < 5; ++f) acc[f][es] = 0.f;
            }
        }
    }
    // reduce 2 waves
#pragma unroll
    for (int o = 32; o > 0; o >>= 1) sum += __shfl_down(sum, o, 64);
    __shared__ float ws2[2];
    if ((tid & 63) == 0) ws2[tid >> 6] = sum;
    __syncthreads();
    if (tid == 0) partials[blockIdx.x] = ws2[0] + ws2[1];
}

// ---------------- final reduce ----------------
__global__ void ssim_final(const float* __restrict__ partial, int n,
                           float* __restrict__ out, double inv_count) {
    int tid = threadIdx.x;
    double s = 0.0;
    for (int i = tid; i < n; i += 256) s += (double)partial[i];
#pragma unroll
    for (int o = 32; o > 0; o >>= 1) s += __shfl_down(s, o, 64);
    __shared__ double wsum[4];
    int lane = tid & 63, wid = tid >> 6;
    if (lane == 0) wsum[wid] = s;
    __syncthreads();
    if (tid == 0)
        out[0] = (float)((wsum[0] + wsum[1] + wsum[2] + wsum[3]) * inv_count);
}

extern "C" void kernel_launch(void* const* d_in, const int* in_sizes, int n_in,
                              void* d_out, int out_size, void* d_ws, size_t ws_size,
                              hipStream_t stream) {
    const float* img1 = (const float*)d_in[0];
    const float* img2 = (const float*)d_in[1];
    float* out = (float*)d_out;

    float* fields   = (float*)d_ws;                    // 20*S floats (167.8 MB)
    float* partials = fields + 20 * (size_t)S;         // 2048 floats

    ssimA<<<2048, 128, 0, stream>>>(img1, img2, fields);
    ssimB<<<2048, 128, 0, stream>>>(fields, partials);
    ssim_final<<<1, 256, 0, stream>>>(partials, 2048, out,
                                      1.0 / ((double)S * 4));
}